// Round 7
// baseline (2056.866 us; speedup 1.0000x reference)
//
#include <hip/hip_runtime.h>
#include <hip/hip_bf16.h>
#include <hip/hip_fp16.h>
#include <math.h>

#define NNODES 500000
#define BN_EPS 1e-5f
#define BKT 512
#define NBKT ((NNODES + BKT - 1) / BKT)          // 977
#define EPB 16384                                 // edges per block in hist/scatter

__device__ __forceinline__ int atomAddI(int* p, int v) {
    return __hip_atomic_fetch_add(p, v, __ATOMIC_RELAXED, __HIP_MEMORY_SCOPE_AGENT);
}
__device__ __forceinline__ void atomAddD(double* p, double v) {
    __hip_atomic_fetch_add(p, v, __ATOMIC_RELAXED, __HIP_MEMORY_SCOPE_AGENT);
}
__device__ __forceinline__ void ldsAddF(float* p, float v) {
    __hip_atomic_fetch_add(p, v, __ATOMIC_RELAXED, __HIP_MEMORY_SCOPE_WORKGROUP);
}

// ---------- block-level reduce (512 threads = 8 waves) of CNT doubles ----------
template<int CNT>
__device__ __forceinline__ void blk_reduce_atomic(double (&vals)[CNT], double* dst) {
    __shared__ double sh[CNT][8];
    int lane = threadIdx.x & 63, wid = threadIdx.x >> 6;
#pragma unroll
    for (int k = 0; k < CNT; ++k) {
        double v = vals[k];
#pragma unroll
        for (int o = 32; o; o >>= 1) v += __shfl_down(v, o);
        if (lane == 0) sh[k][wid] = v;
    }
    __syncthreads();
    if ((int)threadIdx.x < CNT) {
        double v = 0.0;
#pragma unroll
        for (int w = 0; w < 8; ++w) v += sh[threadIdx.x][w];
        atomAddD(dst + threadIdx.x, v);
    }
}

// ---------- tiny: h_row, a0/a1/a2 from weights only ----------
__global__ void k_t0(const float* __restrict__ Wi, const float* __restrict__ bi,
                     const float* __restrict__ Wg, const float* __restrict__ bg,
                     const float* __restrict__ Wt1, float* __restrict__ fs) {
    if (threadIdx.x || blockIdx.x) return;
    float xr[4];
    for (int j = 0; j < 4; ++j) {
        float s = bi[j];
        for (int k = 0; k < 12; ++k) s += Wi[k * 4 + j];
        xr[j] = s;
    }
    float hr[7];
    for (int j = 0; j < 7; ++j) {
        float s = bg[j];
        for (int k = 0; k < 4; ++k) s += xr[k] * Wg[k * 7 + j];
        hr[j] = 1.f / (1.f + expf(-s));
        fs[j] = hr[j];
    }
    for (int j = 0; j < 7; ++j) {
        float s0 = 0.f, s1 = 0.f, s2 = 0.f;
        for (int k = 0; k < 7; ++k) {
            s0 += hr[k] * Wt1[k * 7 + j];
            s1 += hr[k] * Wt1[(7 + k) * 7 + j];
            s2 += hr[k] * Wt1[(14 + k) * 7 + j];
        }
        fs[7 + j] = s0; fs[14 + j] = s1; fs[21 + j] = s2;
    }
}

// ---------- bucket histogram (LDS-privatized) ----------
__global__ void __launch_bounds__(256) k_bhist(const int* __restrict__ dst, int* __restrict__ gcnt, int E) {
    __shared__ int h[NBKT];
    for (int i = threadIdx.x; i < NBKT; i += 256) h[i] = 0;
    __syncthreads();
    int base = blockIdx.x * EPB;
#pragma unroll
    for (int k = 0; k < EPB / 1024; ++k) {
        int i4 = base + (k * 256 + threadIdx.x) * 4;
        if (i4 + 3 < E) {
            int4 d = *reinterpret_cast<const int4*>(dst + i4);
            atomicAdd(&h[d.x >> 9], 1); atomicAdd(&h[d.y >> 9], 1);
            atomicAdd(&h[d.z >> 9], 1); atomicAdd(&h[d.w >> 9], 1);
        } else {
            for (int i = i4; i < E && i < i4 + 4; ++i) atomicAdd(&h[dst[i] >> 9], 1);
        }
    }
    __syncthreads();
    for (int i = threadIdx.x; i < NBKT; i += 256)
        if (h[i]) atomAddI(gcnt + i, h[i]);
}

// ---------- exclusive scan of bucket counts (1 block, 1024 thr) ----------
__global__ void __launch_bounds__(1024) k_bscan(const int* __restrict__ gcnt,
                                                int* __restrict__ bb, int* __restrict__ gcur) {
    __shared__ int sh[1024];
    int t = threadIdx.x;
    int v = (t < NBKT) ? gcnt[t] : 0;
    sh[t] = v; __syncthreads();
    for (int o = 1; o < 1024; o <<= 1) {
        int x = (t >= o) ? sh[t - o] : 0;
        __syncthreads();
        sh[t] += x;
        __syncthreads();
    }
    if (t < NBKT) { int ex = sh[t] - v; bb[t] = ex; gcur[t] = ex; }
    if (t == 0) bb[NBKT] = sh[1023];
}

// ---------- multisplit scatter: packed (dl<<19 | src) ----------
__global__ void __launch_bounds__(256) k_bscat(const int* __restrict__ src, const int* __restrict__ dst,
                                               int* __restrict__ gcur, unsigned int* __restrict__ pairs, int E) {
    __shared__ int h[NBKT];
    for (int i = threadIdx.x; i < NBKT; i += 256) h[i] = 0;
    __syncthreads();
    int base = blockIdx.x * EPB;
#pragma unroll
    for (int k = 0; k < EPB / 1024; ++k) {
        int i4 = base + (k * 256 + threadIdx.x) * 4;
        if (i4 + 3 < E) {
            int4 d = *reinterpret_cast<const int4*>(dst + i4);
            atomicAdd(&h[d.x >> 9], 1); atomicAdd(&h[d.y >> 9], 1);
            atomicAdd(&h[d.z >> 9], 1); atomicAdd(&h[d.w >> 9], 1);
        } else {
            for (int i = i4; i < E && i < i4 + 4; ++i) atomicAdd(&h[dst[i] >> 9], 1);
        }
    }
    __syncthreads();
    for (int i = threadIdx.x; i < NBKT; i += 256) {
        int c = h[i];
        h[i] = c ? atomAddI(gcur + i, c) : 0;
    }
    __syncthreads();
#pragma unroll
    for (int k = 0; k < EPB / 1024; ++k) {
        int i4 = base + (k * 256 + threadIdx.x) * 4;
        if (i4 + 3 < E) {
            int4 s = *reinterpret_cast<const int4*>(src + i4);
            int4 d = *reinterpret_cast<const int4*>(dst + i4);
            int se[4] = {s.x, s.y, s.z, s.w};
            int de[4] = {d.x, d.y, d.z, d.w};
#pragma unroll
            for (int e = 0; e < 4; ++e) {
                int b = de[e] >> 9;
                int pos = atomicAdd(&h[b], 1);
                pairs[pos] = ((unsigned int)(de[e] & 511) << 19) | (unsigned int)se[e];
            }
        } else {
            for (int i = i4; i < E && i < i4 + 4; ++i) {
                int b = dst[i] >> 9;
                int pos = atomicAdd(&h[b], 1);
                pairs[pos] = ((unsigned int)(dst[i] & 511) << 19) | (unsigned int)src[i];
            }
        }
    }
}

// ---------- per-bucket: degree -> nrm array + sc4.zw = (nrm, sdeg) ----------
__global__ void __launch_bounds__(512) k_deg(const unsigned int* __restrict__ pairs, const int* __restrict__ bb,
                                             float* __restrict__ nrm, float* __restrict__ sc4, int n) {
    __shared__ int deg[BKT];
    int b = blockIdx.x, t = threadIdx.x;
    deg[t] = 0;
    __syncthreads();
    int lo = bb[b], hi = bb[b + 1];
    int k = lo + t;
    for (; k + BKT < hi; k += 2 * BKT) {
        unsigned int v1 = pairs[k], v2 = pairs[k + BKT];
        atomicAdd(&deg[v1 >> 19], 1);
        atomicAdd(&deg[v2 >> 19], 1);
    }
    if (k < hi) atomicAdd(&deg[pairs[k] >> 19], 1);
    __syncthreads();
    int node = b * BKT + t;
    if (node < n) {
        float sd = sqrtf((float)(deg[t] > 0 ? deg[t] : 1));
        float nn = 1.f / sd;
        nrm[node] = nn;
        reinterpret_cast<float4*>(sc4)[node] = make_float4(0.f, 0.f, nn, sd);
    }
}

// ---------- per-bucket: s1 = norm * sum norm[src]; s1n = s1*norm; sc4.x = s1 ----------
__global__ void __launch_bounds__(512) k_s1(const unsigned int* __restrict__ pairs, const int* __restrict__ bb,
                                            const float* __restrict__ nrm, float* __restrict__ s1,
                                            float* __restrict__ s1n, float* __restrict__ sc4, int n) {
    __shared__ float acc[BKT];
    int b = blockIdx.x, t = threadIdx.x;
    acc[t] = 0.f;
    __syncthreads();
    int lo = bb[b], hi = bb[b + 1];
    int k = lo + t;
    for (; k + BKT < hi; k += 2 * BKT) {
        unsigned int v1 = pairs[k], v2 = pairs[k + BKT];
        float g1 = nrm[v1 & 0x7FFFF], g2 = nrm[v2 & 0x7FFFF];
        ldsAddF(&acc[v1 >> 19], g1);
        ldsAddF(&acc[v2 >> 19], g2);
    }
    if (k < hi) { unsigned int v = pairs[k]; ldsAddF(&acc[v >> 19], nrm[v & 0x7FFFF]); }
    __syncthreads();
    int node = b * BKT + t;
    if (node < n) {
        float nn = nrm[node], v1 = acc[t] * nn;
        s1[node] = v1; s1n[node] = v1 * nn;
        sc4[(size_t)node * 4 + 0] = v1;
    }
}

// ---------- per-bucket: s2 = norm * sum s1n[src]; sc4.y = s2; + moments ----------
__global__ void __launch_bounds__(512) k_s2(const unsigned int* __restrict__ pairs, const int* __restrict__ bb,
                                            const float* __restrict__ nrm, const float* __restrict__ s1,
                                            const float* __restrict__ s1n, float* __restrict__ sc4,
                                            double* __restrict__ ds, int n) {
    __shared__ float acc[BKT];
    int b = blockIdx.x, t = threadIdx.x;
    acc[t] = 0.f;
    __syncthreads();
    int lo = bb[b], hi = bb[b + 1];
    int k = lo + t;
    for (; k + BKT < hi; k += 2 * BKT) {
        unsigned int v1 = pairs[k], v2 = pairs[k + BKT];
        float g1 = s1n[v1 & 0x7FFFF], g2 = s1n[v2 & 0x7FFFF];
        ldsAddF(&acc[v1 >> 19], g1);
        ldsAddF(&acc[v2 >> 19], g2);
    }
    if (k < hi) { unsigned int v = pairs[k]; ldsAddF(&acc[v >> 19], s1n[v & 0x7FFFF]); }
    __syncthreads();
    double m[5] = {0, 0, 0, 0, 0};
    int node = b * BKT + t;
    if (node < n) {
        float nn = nrm[node], v2 = acc[t] * nn;
        sc4[(size_t)node * 4 + 1] = v2;
        float v1 = s1[node];
        m[0] += v1; m[1] += v2;
        m[2] += (double)v1 * (double)v1;
        m[3] += (double)v2 * (double)v2;
        m[4] += (double)v1 * (double)v2;
    }
    blk_reduce_atomic<5>(m, ds);
}

// ---------- tiny: BN1 folded coefficients d0,d1,d2 ----------
__global__ void k_t1(const double* __restrict__ ds, const float* __restrict__ fs,
                     const float* __restrict__ g1, const float* __restrict__ b1, float* __restrict__ fsg) {
    if (threadIdx.x || blockIdx.x) return;
    const double inv_n = 1.0 / (double)NNODES;
    float mu1 = (float)(ds[0] * inv_n), mu2 = (float)(ds[1] * inv_n);
    float V11 = (float)(ds[2] * inv_n) - mu1 * mu1;
    float V22 = (float)(ds[3] * inv_n) - mu2 * mu2;
    float V12 = (float)(ds[4] * inv_n) - mu1 * mu2;
    for (int j = 0; j < 7; ++j) {
        float a1 = fs[14 + j], a2 = fs[21 + j];
        float var = a1 * a1 * V11 + a2 * a2 * V22 + 2.f * a1 * a2 * V12;
        float ig = (1.f / sqrtf(var + BN_EPS)) * g1[j];
        fsg[j]      = b1[j] - (mu1 * a1 + mu2 * a2) * ig;  // d0
        fsg[7 + j]  = a1 * ig;                              // d1
        fsg[14 + j] = a2 * ig;                              // d2
    }
}

// ---------- per-bucket: f1 gather; h1n computed in-flight from sc4[src]; fp16 rows out ----------
__global__ void __launch_bounds__(512) k_f1(const unsigned int* __restrict__ pairs, const int* __restrict__ bb,
                                            const float* __restrict__ nrm, const float* __restrict__ sc4,
                                            const float* __restrict__ fsg, float* __restrict__ f1nh, int n) {
    __shared__ float a[7][BKT];
    int b = blockIdx.x, t = threadIdx.x;
    float dc[21];
#pragma unroll
    for (int j = 0; j < 21; ++j) dc[j] = fsg[j];
#pragma unroll
    for (int j = 0; j < 7; ++j) a[j][t] = 0.f;
    __syncthreads();
    int lo = bb[b], hi = bb[b + 1];
    int k = lo + t;
    for (; k + BKT < hi; k += 2 * BKT) {
        unsigned int v1 = pairs[k], v2 = pairs[k + BKT];
        float4 r1 = reinterpret_cast<const float4*>(sc4)[v1 & 0x7FFFF];
        float4 r2 = reinterpret_cast<const float4*>(sc4)[v2 & 0x7FFFF];
        int d1 = v1 >> 19, d2 = v2 >> 19;
#pragma unroll
        for (int j = 0; j < 7; ++j) {
            float h = fmaxf(dc[j] + r1.x * dc[7 + j] + r1.y * dc[14 + j], 0.f) * r1.z;
            ldsAddF(&a[j][d1], h);
        }
#pragma unroll
        for (int j = 0; j < 7; ++j) {
            float h = fmaxf(dc[j] + r2.x * dc[7 + j] + r2.y * dc[14 + j], 0.f) * r2.z;
            ldsAddF(&a[j][d2], h);
        }
    }
    if (k < hi) {
        unsigned int v = pairs[k];
        float4 r = reinterpret_cast<const float4*>(sc4)[v & 0x7FFFF];
        int dl = v >> 19;
#pragma unroll
        for (int j = 0; j < 7; ++j) {
            float h = fmaxf(dc[j] + r.x * dc[7 + j] + r.y * dc[14 + j], 0.f) * r.z;
            ldsAddF(&a[j][dl], h);
        }
    }
    __syncthreads();
    int node = b * BKT + t;
    if (node < n) {
        float nn = nrm[node], sc = nn * nn;
        __half2 hh[4];
        hh[0] = __floats2half2_rn(a[0][t] * sc, a[1][t] * sc);
        hh[1] = __floats2half2_rn(a[2][t] * sc, a[3][t] * sc);
        hh[2] = __floats2half2_rn(a[4][t] * sc, a[5][t] * sc);
        hh[3] = __floats2half2_rn(a[6][t] * sc, 0.f);
        reinterpret_cast<float4*>(f1nh)[node] = *reinterpret_cast<float4*>(hh);
    }
}

// ---------- per-bucket fused: f2 gather (fp16 rows) + x2 = [h1|f1p|f2p]@Wt2 + BN2 moments ----------
__global__ void __launch_bounds__(512) k_x2f(const unsigned int* __restrict__ pairs, const int* __restrict__ bb,
                                             const float* __restrict__ sc4, const float* __restrict__ fsg,
                                             const float* __restrict__ f1nh, const float* __restrict__ Wt2,
                                             float* __restrict__ x2o, double* __restrict__ ds, int n) {
    __shared__ float a[7][BKT];
    __shared__ float w[147];
    int b = blockIdx.x, t = threadIdx.x;
    for (int k = t; k < 147; k += 512) w[k] = Wt2[k];
    float dc[21];
#pragma unroll
    for (int j = 0; j < 21; ++j) dc[j] = fsg[j];
#pragma unroll
    for (int j = 0; j < 7; ++j) a[j][t] = 0.f;
    __syncthreads();
    int lo = bb[b], hi = bb[b + 1];
    int k = lo + t;
    for (; k + BKT < hi; k += 2 * BKT) {
        unsigned int v1 = pairs[k], v2 = pairs[k + BKT];
        float4 raw1 = reinterpret_cast<const float4*>(f1nh)[v1 & 0x7FFFF];
        float4 raw2 = reinterpret_cast<const float4*>(f1nh)[v2 & 0x7FFFF];
        int d1 = v1 >> 19, d2 = v2 >> 19;
        {
            const __half2* hp = reinterpret_cast<const __half2*>(&raw1);
            float2 q0 = __half22float2(hp[0]), q1 = __half22float2(hp[1]);
            float2 q2 = __half22float2(hp[2]), q3 = __half22float2(hp[3]);
            ldsAddF(&a[0][d1], q0.x); ldsAddF(&a[1][d1], q0.y); ldsAddF(&a[2][d1], q1.x);
            ldsAddF(&a[3][d1], q1.y); ldsAddF(&a[4][d1], q2.x); ldsAddF(&a[5][d1], q2.y);
            ldsAddF(&a[6][d1], q3.x);
        }
        {
            const __half2* hp = reinterpret_cast<const __half2*>(&raw2);
            float2 q0 = __half22float2(hp[0]), q1 = __half22float2(hp[1]);
            float2 q2 = __half22float2(hp[2]), q3 = __half22float2(hp[3]);
            ldsAddF(&a[0][d2], q0.x); ldsAddF(&a[1][d2], q0.y); ldsAddF(&a[2][d2], q1.x);
            ldsAddF(&a[3][d2], q1.y); ldsAddF(&a[4][d2], q2.x); ldsAddF(&a[5][d2], q2.y);
            ldsAddF(&a[6][d2], q3.x);
        }
    }
    if (k < hi) {
        unsigned int v = pairs[k];
        float4 raw = reinterpret_cast<const float4*>(f1nh)[v & 0x7FFFF];
        int dl = v >> 19;
        const __half2* hp = reinterpret_cast<const __half2*>(&raw);
        float2 q0 = __half22float2(hp[0]), q1 = __half22float2(hp[1]);
        float2 q2 = __half22float2(hp[2]), q3 = __half22float2(hp[3]);
        ldsAddF(&a[0][dl], q0.x); ldsAddF(&a[1][dl], q0.y); ldsAddF(&a[2][dl], q1.x);
        ldsAddF(&a[3][dl], q1.y); ldsAddF(&a[4][dl], q2.x); ldsAddF(&a[5][dl], q2.y);
        ldsAddF(&a[6][dl], q3.x);
    }
    __syncthreads();
    double sx[7] = {0, 0, 0, 0, 0, 0, 0}, sq[7] = {0, 0, 0, 0, 0, 0, 0};
    int node = b * BKT + t;
    if (node < n) {
        float4 s = reinterpret_cast<const float4*>(sc4)[node];   // (s1,s2,nrm,sdeg)
        float S1 = s.x, S2 = s.y, Nn = s.z, rn = s.w;
        float h1[7];
#pragma unroll
        for (int kk = 0; kk < 7; ++kk) h1[kk] = fmaxf(dc[kk] + S1 * dc[7 + kk] + S2 * dc[14 + kk], 0.f);
        float4 raw = reinterpret_cast<const float4*>(f1nh)[node];
        const __half2* hp = reinterpret_cast<const __half2*>(&raw);
        float2 q0 = __half22float2(hp[0]), q1 = __half22float2(hp[1]);
        float2 q2 = __half22float2(hp[2]), q3 = __half22float2(hp[3]);
        float f1p[7] = {q0.x * rn, q0.y * rn, q1.x * rn, q1.y * rn, q2.x * rn, q2.y * rn, q3.x * rn};
        float f2p[7];
#pragma unroll
        for (int kk = 0; kk < 7; ++kk) f2p[kk] = a[kk][t] * Nn;
        float x2[8];
#pragma unroll
        for (int j = 0; j < 7; ++j) {
            float sacc = 0.f;
#pragma unroll
            for (int kk = 0; kk < 7; ++kk)
                sacc += h1[kk] * w[kk * 7 + j] + f1p[kk] * w[(7 + kk) * 7 + j] + f2p[kk] * w[(14 + kk) * 7 + j];
            x2[j] = sacc;
            sx[j] += sacc; sq[j] += (double)sacc * (double)sacc;
        }
        x2[7] = 0.f;
        float4* q = reinterpret_cast<float4*>(x2o + (size_t)node * 8);
        q[0] = make_float4(x2[0], x2[1], x2[2], x2[3]);
        q[1] = make_float4(x2[4], x2[5], x2[6], x2[7]);
    }
    double acc[14];
#pragma unroll
    for (int j = 0; j < 7; ++j) { acc[j] = sx[j]; acc[7 + j] = sq[j]; }
    blk_reduce_atomic<14>(acc, ds + 5);
}

// ---------- tiny: BN2 folded coefficients c0,c1 ----------
__global__ void k_t2(const double* __restrict__ ds, const float* __restrict__ g2,
                     const float* __restrict__ b2, float* __restrict__ fsg) {
    if (threadIdx.x || blockIdx.x) return;
    const double inv_n = 1.0 / (double)NNODES;
    for (int j = 0; j < 7; ++j) {
        float m = (float)(ds[5 + j] * inv_n);
        float v = (float)(ds[12 + j] * inv_n) - m * m;
        float ig = (1.f / sqrtf(v + BN_EPS)) * g2[j];
        fsg[21 + j] = b2[j] - m * ig;  // c0
        fsg[28 + j] = ig;              // c1
    }
}

// ---------- node: h2 column sums ----------
__global__ void __launch_bounds__(512) k_h2sum(const float* __restrict__ x2o, const float* __restrict__ fsg,
                                               double* __restrict__ ds, int n) {
    float c0[7], c1[7];
#pragma unroll
    for (int j = 0; j < 7; ++j) { c0[j] = fsg[21 + j]; c1[j] = fsg[28 + j]; }
    double acc[7] = {0, 0, 0, 0, 0, 0, 0};
    for (int i = blockIdx.x * blockDim.x + threadIdx.x; i < n; i += gridDim.x * blockDim.x) {
        const float4* p = reinterpret_cast<const float4*>(x2o + (size_t)i * 8);
        float4 a = p[0], b = p[1];
        float x[7] = {a.x, a.y, a.z, a.w, b.x, b.y, b.z};
#pragma unroll
        for (int j = 0; j < 7; ++j) acc[j] += (double)fmaxf(x[j] * c1[j] + c0[j], 0.f);
    }
    blk_reduce_atomic<7>(acc, ds + 19);
}

// ---------- tiny: embeddings + similarity MLP + sigmoid ----------
__global__ void k_final(const double* __restrict__ ds, const float* __restrict__ Wd, const float* __restrict__ bd,
                        const float* __restrict__ Ws0, const float* __restrict__ bs0,
                        const float* __restrict__ Ws1, const float* __restrict__ bs1,
                        const float* __restrict__ Ws2, const float* __restrict__ bs2,
                        const float* __restrict__ Ws3, const float* __restrict__ bs3,
                        const float* __restrict__ Wsim, const float* __restrict__ bsim,
                        float* __restrict__ out) {
    if (threadIdx.x || blockIdx.x) return;
    const double inv_n = 1.0 / (double)NNODES;
    float v[22];
    for (int g = 0; g < 2; ++g) {
        float hm[7];
        for (int j = 0; j < 7; ++j) hm[j] = (float)(ds[g * 26 + 19 + j] * inv_n);
        for (int r = 0; r < 11; ++r) {
            float s = bd[r];
            for (int j = 0; j < 7; ++j) s += hm[j] * Wd[j * 11 + r];
            v[g * 11 + r] = s;
        }
    }
    float h[7], h2[7];
    for (int j = 0; j < 7; ++j) {
        float s = bs0[j];
        for (int k = 0; k < 22; ++k) s += v[k] * Ws0[k * 7 + j];
        h[j] = s;
    }
    const float* Ws[3] = {Ws1, Ws2, Ws3};
    const float* bs[3] = {bs1, bs2, bs3};
    for (int l = 0; l < 3; ++l) {
        for (int j = 0; j < 7; ++j) {
            float s = bs[l][j];
            for (int k = 0; k < 7; ++k) s += h[k] * Ws[l][k * 7 + j];
            h2[j] = fmaxf(s, 0.f);
        }
        for (int j = 0; j < 7; ++j) h[j] = h2[j];
    }
    for (int r = 0; r < 12; ++r) {
        float s = bsim[r];
        for (int j = 0; j < 7; ++j) s += h[j] * Wsim[j * 12 + r];
        out[r] = 1.f / (1.f + expf(-s));
    }
}

extern "C" void kernel_launch(void* const* d_in, const int* in_sizes, int n_in,
                              void* d_out, int out_size, void* d_ws, size_t ws_size,
                              hipStream_t stream) {
    const int E = in_sizes[0];
    const int n = NNODES;
    const int* src1 = (const int*)d_in[0];
    const int* dst1 = (const int*)d_in[1];
    const int* src2 = (const int*)d_in[2];
    const int* dst2 = (const int*)d_in[3];
    const float* W_init = (const float*)d_in[5];
    const float* b_init = (const float*)d_in[6];
    const float* Wg  = (const float*)d_in[7];
    const float* bg  = (const float*)d_in[8];
    const float* Wt1 = (const float*)d_in[9];
    const float* g1  = (const float*)d_in[10];
    const float* b1  = (const float*)d_in[11];
    const float* Wt2 = (const float*)d_in[12];
    const float* g2  = (const float*)d_in[13];
    const float* b2  = (const float*)d_in[14];
    const float* Wd  = (const float*)d_in[15];
    const float* bd  = (const float*)d_in[16];
    const float* Ws0 = (const float*)d_in[17];
    const float* bs0 = (const float*)d_in[18];
    const float* Ws1 = (const float*)d_in[19];
    const float* bs1 = (const float*)d_in[20];
    const float* Ws2 = (const float*)d_in[21];
    const float* bs2 = (const float*)d_in[22];
    const float* Ws3 = (const float*)d_in[23];
    const float* bs3 = (const float*)d_in[24];
    const float* Wsim = (const float*)d_in[25];
    const float* bsim = (const float*)d_in[26];

    // scalars first (1 KiB), then 16B-aligned arrays: 19n floats + 32MB pairs ≈ 70 MB
    double* dscal = (double*)d_ws;                     // 52 doubles
    float* fscal  = (float*)(dscal + 52);              // 128 floats
    float* F      = (float*)((char*)d_ws + 1024);
    float* nrm  = F;                                   // n
    float* s1   = F + (size_t)n;                       // n
    float* s1n  = F + 2 * (size_t)n;                   // n
    float* sc4  = F + 3 * (size_t)n;                   // 4n (s1,s2,nrm,sdeg)
    float* f1nh = F + 7 * (size_t)n;                   // 4n float-slots = 16B fp16 rows
    float* x2o  = F + 11 * (size_t)n;                  // 8n
    int*   gcnt = (int*)(F + 19 * (size_t)n);          // NBKT
    int*   bb   = gcnt + NBKT;                         // NBKT+1
    int*   gcur = bb + NBKT + 1;                       // NBKT
    unsigned int* pairs = (unsigned int*)(gcur + NBKT);// E

    const int EB = (E + EPB - 1) / EPB;

    hipMemsetAsync(dscal, 0, 52 * sizeof(double), stream);
    k_t0<<<1, 1, 0, stream>>>(W_init, b_init, Wg, bg, Wt1, fscal);

    for (int g = 0; g < 2; ++g) {
        const int* src = g ? src2 : src1;
        const int* dst = g ? dst2 : dst1;
        float* fsg  = fscal + 28 + g * 35;
        double* dsg = dscal + g * 26;

        hipMemsetAsync(gcnt, 0, NBKT * sizeof(int), stream);
        k_bhist<<<EB, 256, 0, stream>>>(dst, gcnt, E);
        k_bscan<<<1, 1024, 0, stream>>>(gcnt, bb, gcur);
        k_bscat<<<EB, 256, 0, stream>>>(src, dst, gcur, pairs, E);

        k_deg<<<NBKT, 512, 0, stream>>>(pairs, bb, nrm, sc4, n);
        k_s1 <<<NBKT, 512, 0, stream>>>(pairs, bb, nrm, s1, s1n, sc4, n);
        k_s2 <<<NBKT, 512, 0, stream>>>(pairs, bb, nrm, s1, s1n, sc4, dsg, n);
        k_t1<<<1, 1, 0, stream>>>(dsg, fscal, g1, b1, fsg);
        k_f1 <<<NBKT, 512, 0, stream>>>(pairs, bb, nrm, sc4, fsg, f1nh, n);
        k_x2f<<<NBKT, 512, 0, stream>>>(pairs, bb, sc4, fsg, f1nh, Wt2, x2o, dsg, n);
        k_t2<<<1, 1, 0, stream>>>(dsg, g2, b2, fsg);
        k_h2sum<<<512, 512, 0, stream>>>(x2o, fsg, dsg, n);
    }
    k_final<<<1, 1, 0, stream>>>(dscal, Wd, bd, Ws0, bs0, Ws1, bs1, Ws2, bs2, Ws3, bs3,
                                 Wsim, bsim, (float*)d_out);
}

// Round 8
// 2011.351 us; speedup vs baseline: 1.0226x; 1.0226x over previous
//
#include <hip/hip_runtime.h>
#include <hip/hip_bf16.h>
#include <hip/hip_fp16.h>
#include <math.h>

#define NNODES 500000
#define BN_EPS 1e-5f
#define BKT 512
#define NBKT ((NNODES + BKT - 1) / BKT)          // 977
#define EPB 16384                                 // edges per block in hist/scatter

__device__ __forceinline__ int atomAddI(int* p, int v) {
    return __hip_atomic_fetch_add(p, v, __ATOMIC_RELAXED, __HIP_MEMORY_SCOPE_AGENT);
}
__device__ __forceinline__ void atomAddD(double* p, double v) {
    __hip_atomic_fetch_add(p, v, __ATOMIC_RELAXED, __HIP_MEMORY_SCOPE_AGENT);
}
__device__ __forceinline__ void ldsAddF(float* p, float v) {
    __hip_atomic_fetch_add(p, v, __ATOMIC_RELAXED, __HIP_MEMORY_SCOPE_WORKGROUP);
}

// ---------- block-level reduce (512 threads = 8 waves) of CNT doubles ----------
template<int CNT>
__device__ __forceinline__ void blk_reduce_atomic(double (&vals)[CNT], double* dst) {
    __shared__ double sh[CNT][8];
    int lane = threadIdx.x & 63, wid = threadIdx.x >> 6;
#pragma unroll
    for (int k = 0; k < CNT; ++k) {
        double v = vals[k];
#pragma unroll
        for (int o = 32; o; o >>= 1) v += __shfl_down(v, o);
        if (lane == 0) sh[k][wid] = v;
    }
    __syncthreads();
    if ((int)threadIdx.x < CNT) {
        double v = 0.0;
#pragma unroll
        for (int w = 0; w < 8; ++w) v += sh[threadIdx.x][w];
        atomAddD(dst + threadIdx.x, v);
    }
}

// ---------- tiny: h_row, a0/a1/a2 from weights only ----------
__global__ void k_t0(const float* __restrict__ Wi, const float* __restrict__ bi,
                     const float* __restrict__ Wg, const float* __restrict__ bg,
                     const float* __restrict__ Wt1, float* __restrict__ fs) {
    if (threadIdx.x || blockIdx.x) return;
    float xr[4];
    for (int j = 0; j < 4; ++j) {
        float s = bi[j];
        for (int k = 0; k < 12; ++k) s += Wi[k * 4 + j];
        xr[j] = s;
    }
    float hr[7];
    for (int j = 0; j < 7; ++j) {
        float s = bg[j];
        for (int k = 0; k < 4; ++k) s += xr[k] * Wg[k * 7 + j];
        hr[j] = 1.f / (1.f + expf(-s));
        fs[j] = hr[j];
    }
    for (int j = 0; j < 7; ++j) {
        float s0 = 0.f, s1 = 0.f, s2 = 0.f;
        for (int k = 0; k < 7; ++k) {
            s0 += hr[k] * Wt1[k * 7 + j];
            s1 += hr[k] * Wt1[(7 + k) * 7 + j];
            s2 += hr[k] * Wt1[(14 + k) * 7 + j];
        }
        fs[7 + j] = s0; fs[14 + j] = s1; fs[21 + j] = s2;
    }
}

// ---------- bucket histogram (LDS-privatized) ----------
__global__ void __launch_bounds__(512) k_bhist(const int* __restrict__ dst, int* __restrict__ gcnt, int E) {
    __shared__ int h[NBKT];
    for (int i = threadIdx.x; i < NBKT; i += 512) h[i] = 0;
    __syncthreads();
    int base = blockIdx.x * EPB;
#pragma unroll
    for (int k = 0; k < EPB / 2048; ++k) {
        int i4 = base + (k * 512 + threadIdx.x) * 4;
        if (i4 + 3 < E) {
            int4 d = *reinterpret_cast<const int4*>(dst + i4);
            atomicAdd(&h[d.x >> 9], 1); atomicAdd(&h[d.y >> 9], 1);
            atomicAdd(&h[d.z >> 9], 1); atomicAdd(&h[d.w >> 9], 1);
        } else {
            for (int i = i4; i < E && i < i4 + 4; ++i) atomicAdd(&h[dst[i] >> 9], 1);
        }
    }
    __syncthreads();
    for (int i = threadIdx.x; i < NBKT; i += 512)
        if (h[i]) atomAddI(gcnt + i, h[i]);
}

// ---------- exclusive scan of bucket counts (1 block, 1024 thr) ----------
__global__ void __launch_bounds__(1024) k_bscan(const int* __restrict__ gcnt,
                                                int* __restrict__ bb, int* __restrict__ gcur) {
    __shared__ int sh[1024];
    int t = threadIdx.x;
    int v = (t < NBKT) ? gcnt[t] : 0;
    sh[t] = v; __syncthreads();
    for (int o = 1; o < 1024; o <<= 1) {
        int x = (t >= o) ? sh[t - o] : 0;
        __syncthreads();
        sh[t] += x;
        __syncthreads();
    }
    if (t < NBKT) { int ex = sh[t] - v; bb[t] = ex; gcur[t] = ex; }
    if (t == 0) bb[NBKT] = sh[1023];
}

// ---------- multisplit scatter: packed (dl<<19 | src) ----------
__global__ void __launch_bounds__(512) k_bscat(const int* __restrict__ src, const int* __restrict__ dst,
                                               int* __restrict__ gcur, unsigned int* __restrict__ pairs, int E) {
    __shared__ int h[NBKT];
    for (int i = threadIdx.x; i < NBKT; i += 512) h[i] = 0;
    __syncthreads();
    int base = blockIdx.x * EPB;
#pragma unroll
    for (int k = 0; k < EPB / 2048; ++k) {
        int i4 = base + (k * 512 + threadIdx.x) * 4;
        if (i4 + 3 < E) {
            int4 d = *reinterpret_cast<const int4*>(dst + i4);
            atomicAdd(&h[d.x >> 9], 1); atomicAdd(&h[d.y >> 9], 1);
            atomicAdd(&h[d.z >> 9], 1); atomicAdd(&h[d.w >> 9], 1);
        } else {
            for (int i = i4; i < E && i < i4 + 4; ++i) atomicAdd(&h[dst[i] >> 9], 1);
        }
    }
    __syncthreads();
    for (int i = threadIdx.x; i < NBKT; i += 512) {
        int c = h[i];
        h[i] = c ? atomAddI(gcur + i, c) : 0;
    }
    __syncthreads();
#pragma unroll
    for (int k = 0; k < EPB / 2048; ++k) {
        int i4 = base + (k * 512 + threadIdx.x) * 4;
        if (i4 + 3 < E) {
            int4 s = *reinterpret_cast<const int4*>(src + i4);
            int4 d = *reinterpret_cast<const int4*>(dst + i4);
            int se[4] = {s.x, s.y, s.z, s.w};
            int de[4] = {d.x, d.y, d.z, d.w};
#pragma unroll
            for (int e = 0; e < 4; ++e) {
                int b = de[e] >> 9;
                int pos = atomicAdd(&h[b], 1);
                pairs[pos] = ((unsigned int)(de[e] & 511) << 19) | (unsigned int)se[e];
            }
        } else {
            for (int i = i4; i < E && i < i4 + 4; ++i) {
                int b = dst[i] >> 9;
                int pos = atomicAdd(&h[b], 1);
                pairs[pos] = ((unsigned int)(dst[i] & 511) << 19) | (unsigned int)src[i];
            }
        }
    }
}

// ---------- per-bucket: degree -> nrm array + sc4.zw = (nrm, sdeg) ----------
__global__ void __launch_bounds__(512) k_deg(const unsigned int* __restrict__ pairs, const int* __restrict__ bb,
                                             float* __restrict__ nrm, float* __restrict__ sc4, int n) {
    __shared__ int deg[BKT];
    int b = blockIdx.x, t = threadIdx.x;
    deg[t] = 0;
    __syncthreads();
    int lo = bb[b], hi = bb[b + 1];
    int k = lo + t;
    for (; k + 3 * BKT < hi; k += 4 * BKT) {
        unsigned int v1 = pairs[k], v2 = pairs[k + BKT];
        unsigned int v3 = pairs[k + 2 * BKT], v4 = pairs[k + 3 * BKT];
        atomicAdd(&deg[v1 >> 19], 1); atomicAdd(&deg[v2 >> 19], 1);
        atomicAdd(&deg[v3 >> 19], 1); atomicAdd(&deg[v4 >> 19], 1);
    }
    for (; k < hi; k += BKT) atomicAdd(&deg[pairs[k] >> 19], 1);
    __syncthreads();
    int node = b * BKT + t;
    if (node < n) {
        float sd = sqrtf((float)(deg[t] > 0 ? deg[t] : 1));
        float nn = 1.f / sd;
        nrm[node] = nn;
        reinterpret_cast<float4*>(sc4)[node] = make_float4(0.f, 0.f, nn, sd);
    }
}

// ---------- per-bucket: s1 = norm * sum norm[src]; s1n = s1*norm; sc4.x = s1 ----------
__global__ void __launch_bounds__(512) k_s1(const unsigned int* __restrict__ pairs, const int* __restrict__ bb,
                                            const float* __restrict__ nrm, float* __restrict__ s1,
                                            float* __restrict__ s1n, float* __restrict__ sc4, int n) {
    __shared__ float acc[BKT];
    int b = blockIdx.x, t = threadIdx.x;
    acc[t] = 0.f;
    __syncthreads();
    int lo = bb[b], hi = bb[b + 1];
    int k = lo + t;
    for (; k + 3 * BKT < hi; k += 4 * BKT) {
        unsigned int v1 = pairs[k], v2 = pairs[k + BKT];
        unsigned int v3 = pairs[k + 2 * BKT], v4 = pairs[k + 3 * BKT];
        float g1 = nrm[v1 & 0x7FFFF], g2 = nrm[v2 & 0x7FFFF];
        float g3 = nrm[v3 & 0x7FFFF], g4 = nrm[v4 & 0x7FFFF];
        ldsAddF(&acc[v1 >> 19], g1); ldsAddF(&acc[v2 >> 19], g2);
        ldsAddF(&acc[v3 >> 19], g3); ldsAddF(&acc[v4 >> 19], g4);
    }
    for (; k < hi; k += BKT) { unsigned int v = pairs[k]; ldsAddF(&acc[v >> 19], nrm[v & 0x7FFFF]); }
    __syncthreads();
    int node = b * BKT + t;
    if (node < n) {
        float nn = nrm[node], v1 = acc[t] * nn;
        s1[node] = v1; s1n[node] = v1 * nn;
        sc4[(size_t)node * 4 + 0] = v1;
    }
}

// ---------- per-bucket: s2 = norm * sum s1n[src]; sc4.y = s2; sch fp16; + moments ----------
__global__ void __launch_bounds__(512) k_s2(const unsigned int* __restrict__ pairs, const int* __restrict__ bb,
                                            const float* __restrict__ nrm, const float* __restrict__ s1,
                                            const float* __restrict__ s1n, float* __restrict__ sc4,
                                            float* __restrict__ sch, double* __restrict__ ds, int n) {
    __shared__ float acc[BKT];
    int b = blockIdx.x, t = threadIdx.x;
    acc[t] = 0.f;
    __syncthreads();
    int lo = bb[b], hi = bb[b + 1];
    int k = lo + t;
    for (; k + 3 * BKT < hi; k += 4 * BKT) {
        unsigned int v1 = pairs[k], v2 = pairs[k + BKT];
        unsigned int v3 = pairs[k + 2 * BKT], v4 = pairs[k + 3 * BKT];
        float g1 = s1n[v1 & 0x7FFFF], g2 = s1n[v2 & 0x7FFFF];
        float g3 = s1n[v3 & 0x7FFFF], g4 = s1n[v4 & 0x7FFFF];
        ldsAddF(&acc[v1 >> 19], g1); ldsAddF(&acc[v2 >> 19], g2);
        ldsAddF(&acc[v3 >> 19], g3); ldsAddF(&acc[v4 >> 19], g4);
    }
    for (; k < hi; k += BKT) { unsigned int v = pairs[k]; ldsAddF(&acc[v >> 19], s1n[v & 0x7FFFF]); }
    __syncthreads();
    double m[5] = {0, 0, 0, 0, 0};
    int node = b * BKT + t;
    if (node < n) {
        float nn = nrm[node], v2 = acc[t] * nn;
        sc4[(size_t)node * 4 + 1] = v2;
        float v1 = s1[node];
        __half2 p0 = __floats2half2_rn(v1, v2);
        __half2 p1 = __floats2half2_rn(nn, 0.f);
        float2 packed = make_float2(__uint_as_float(*(unsigned int*)&p0),
                                    __uint_as_float(*(unsigned int*)&p1));
        reinterpret_cast<float2*>(sch)[node] = packed;
        m[0] += v1; m[1] += v2;
        m[2] += (double)v1 * (double)v1;
        m[3] += (double)v2 * (double)v2;
        m[4] += (double)v1 * (double)v2;
    }
    blk_reduce_atomic<5>(m, ds);
}

// ---------- tiny: BN1 folded coefficients d0,d1,d2 ----------
__global__ void k_t1(const double* __restrict__ ds, const float* __restrict__ fs,
                     const float* __restrict__ g1, const float* __restrict__ b1, float* __restrict__ fsg) {
    if (threadIdx.x || blockIdx.x) return;
    const double inv_n = 1.0 / (double)NNODES;
    float mu1 = (float)(ds[0] * inv_n), mu2 = (float)(ds[1] * inv_n);
    float V11 = (float)(ds[2] * inv_n) - mu1 * mu1;
    float V22 = (float)(ds[3] * inv_n) - mu2 * mu2;
    float V12 = (float)(ds[4] * inv_n) - mu1 * mu2;
    for (int j = 0; j < 7; ++j) {
        float a1 = fs[14 + j], a2 = fs[21 + j];
        float var = a1 * a1 * V11 + a2 * a2 * V22 + 2.f * a1 * a2 * V12;
        float ig = (1.f / sqrtf(var + BN_EPS)) * g1[j];
        fsg[j]      = b1[j] - (mu1 * a1 + mu2 * a2) * ig;  // d0
        fsg[7 + j]  = a1 * ig;                              // d1
        fsg[14 + j] = a2 * ig;                              // d2
    }
}

__device__ __forceinline__ void f1_edge(const float2 r, const float* dc, float (&sarr)[7][BKT], int dl) {
    unsigned int u0 = __float_as_uint(r.x), u1 = __float_as_uint(r.y);
    __half2 h0 = *(__half2*)&u0, h1v = *(__half2*)&u1;
    float2 q0 = __half22float2(h0), q1 = __half22float2(h1v);
    float S1 = q0.x, S2 = q0.y, Nn = q1.x;
#pragma unroll
    for (int j = 0; j < 7; ++j) {
        float h = fmaxf(dc[j] + S1 * dc[7 + j] + S2 * dc[14 + j], 0.f) * Nn;
        ldsAddF(&sarr[j][dl], h);
    }
}

// ---------- per-bucket: f1 gather (8B fp16 sch rows); fp16 rows out ----------
__global__ void __launch_bounds__(512) k_f1(const unsigned int* __restrict__ pairs, const int* __restrict__ bb,
                                            const float* __restrict__ nrm, const float* __restrict__ sch,
                                            const float* __restrict__ fsg, float* __restrict__ f1nh, int n) {
    __shared__ float a[7][BKT];
    int b = blockIdx.x, t = threadIdx.x;
    float dc[21];
#pragma unroll
    for (int j = 0; j < 21; ++j) dc[j] = fsg[j];
#pragma unroll
    for (int j = 0; j < 7; ++j) a[j][t] = 0.f;
    __syncthreads();
    int lo = bb[b], hi = bb[b + 1];
    int k = lo + t;
    for (; k + 3 * BKT < hi; k += 4 * BKT) {
        unsigned int v1 = pairs[k], v2 = pairs[k + BKT];
        unsigned int v3 = pairs[k + 2 * BKT], v4 = pairs[k + 3 * BKT];
        float2 r1 = reinterpret_cast<const float2*>(sch)[v1 & 0x7FFFF];
        float2 r2 = reinterpret_cast<const float2*>(sch)[v2 & 0x7FFFF];
        float2 r3 = reinterpret_cast<const float2*>(sch)[v3 & 0x7FFFF];
        float2 r4 = reinterpret_cast<const float2*>(sch)[v4 & 0x7FFFF];
        f1_edge(r1, dc, a, v1 >> 19);
        f1_edge(r2, dc, a, v2 >> 19);
        f1_edge(r3, dc, a, v3 >> 19);
        f1_edge(r4, dc, a, v4 >> 19);
    }
    for (; k < hi; k += BKT) {
        unsigned int v = pairs[k];
        float2 r = reinterpret_cast<const float2*>(sch)[v & 0x7FFFF];
        f1_edge(r, dc, a, v >> 19);
    }
    __syncthreads();
    int node = b * BKT + t;
    if (node < n) {
        float nn = nrm[node], sc = nn * nn;
        __half2 hh[4];
        hh[0] = __floats2half2_rn(a[0][t] * sc, a[1][t] * sc);
        hh[1] = __floats2half2_rn(a[2][t] * sc, a[3][t] * sc);
        hh[2] = __floats2half2_rn(a[4][t] * sc, a[5][t] * sc);
        hh[3] = __floats2half2_rn(a[6][t] * sc, 0.f);
        reinterpret_cast<float4*>(f1nh)[node] = *reinterpret_cast<float4*>(hh);
    }
}

__device__ __forceinline__ void x2_edge(const float4 raw, float (&sarr)[7][BKT], int dl) {
    const __half2* hp = reinterpret_cast<const __half2*>(&raw);
    float2 q0 = __half22float2(hp[0]), q1 = __half22float2(hp[1]);
    float2 q2 = __half22float2(hp[2]), q3 = __half22float2(hp[3]);
    ldsAddF(&sarr[0][dl], q0.x); ldsAddF(&sarr[1][dl], q0.y); ldsAddF(&sarr[2][dl], q1.x);
    ldsAddF(&sarr[3][dl], q1.y); ldsAddF(&sarr[4][dl], q2.x); ldsAddF(&sarr[5][dl], q2.y);
    ldsAddF(&sarr[6][dl], q3.x);
}

// ---------- per-bucket fused: f2 gather (fp16 rows) + x2 = [h1|f1p|f2p]@Wt2 + BN2 moments ----------
__global__ void __launch_bounds__(512) k_x2f(const unsigned int* __restrict__ pairs, const int* __restrict__ bb,
                                             const float* __restrict__ sc4, const float* __restrict__ fsg,
                                             const float* __restrict__ f1nh, const float* __restrict__ Wt2,
                                             float* __restrict__ x2o, double* __restrict__ ds, int n) {
    __shared__ float a[7][BKT];
    __shared__ float w[147];
    int b = blockIdx.x, t = threadIdx.x;
    for (int k = t; k < 147; k += 512) w[k] = Wt2[k];
    float dc[21];
#pragma unroll
    for (int j = 0; j < 21; ++j) dc[j] = fsg[j];
#pragma unroll
    for (int j = 0; j < 7; ++j) a[j][t] = 0.f;
    __syncthreads();
    int lo = bb[b], hi = bb[b + 1];
    int k = lo + t;
    for (; k + 3 * BKT < hi; k += 4 * BKT) {
        unsigned int v1 = pairs[k], v2 = pairs[k + BKT];
        unsigned int v3 = pairs[k + 2 * BKT], v4 = pairs[k + 3 * BKT];
        float4 r1 = reinterpret_cast<const float4*>(f1nh)[v1 & 0x7FFFF];
        float4 r2 = reinterpret_cast<const float4*>(f1nh)[v2 & 0x7FFFF];
        float4 r3 = reinterpret_cast<const float4*>(f1nh)[v3 & 0x7FFFF];
        float4 r4 = reinterpret_cast<const float4*>(f1nh)[v4 & 0x7FFFF];
        x2_edge(r1, a, v1 >> 19);
        x2_edge(r2, a, v2 >> 19);
        x2_edge(r3, a, v3 >> 19);
        x2_edge(r4, a, v4 >> 19);
    }
    for (; k < hi; k += BKT) {
        unsigned int v = pairs[k];
        float4 raw = reinterpret_cast<const float4*>(f1nh)[v & 0x7FFFF];
        x2_edge(raw, a, v >> 19);
    }
    __syncthreads();
    double sx[7] = {0, 0, 0, 0, 0, 0, 0}, sq[7] = {0, 0, 0, 0, 0, 0, 0};
    int node = b * BKT + t;
    if (node < n) {
        float4 s = reinterpret_cast<const float4*>(sc4)[node];   // (s1,s2,nrm,sdeg)
        float S1 = s.x, S2 = s.y, Nn = s.z, rn = s.w;
        float h1[7];
#pragma unroll
        for (int kk = 0; kk < 7; ++kk) h1[kk] = fmaxf(dc[kk] + S1 * dc[7 + kk] + S2 * dc[14 + kk], 0.f);
        float4 raw = reinterpret_cast<const float4*>(f1nh)[node];
        const __half2* hp = reinterpret_cast<const __half2*>(&raw);
        float2 q0 = __half22float2(hp[0]), q1 = __half22float2(hp[1]);
        float2 q2 = __half22float2(hp[2]), q3 = __half22float2(hp[3]);
        float f1p[7] = {q0.x * rn, q0.y * rn, q1.x * rn, q1.y * rn, q2.x * rn, q2.y * rn, q3.x * rn};
        float f2p[7];
#pragma unroll
        for (int kk = 0; kk < 7; ++kk) f2p[kk] = a[kk][t] * Nn;
        float x2[8];
#pragma unroll
        for (int j = 0; j < 7; ++j) {
            float sacc = 0.f;
#pragma unroll
            for (int kk = 0; kk < 7; ++kk)
                sacc += h1[kk] * w[kk * 7 + j] + f1p[kk] * w[(7 + kk) * 7 + j] + f2p[kk] * w[(14 + kk) * 7 + j];
            x2[j] = sacc;
            sx[j] += sacc; sq[j] += (double)sacc * (double)sacc;
        }
        x2[7] = 0.f;
        float4* q = reinterpret_cast<float4*>(x2o + (size_t)node * 8);
        q[0] = make_float4(x2[0], x2[1], x2[2], x2[3]);
        q[1] = make_float4(x2[4], x2[5], x2[6], x2[7]);
    }
    double acc[14];
#pragma unroll
    for (int j = 0; j < 7; ++j) { acc[j] = sx[j]; acc[7 + j] = sq[j]; }
    blk_reduce_atomic<14>(acc, ds + 5);
}

// ---------- tiny: BN2 folded coefficients c0,c1 ----------
__global__ void k_t2(const double* __restrict__ ds, const float* __restrict__ g2,
                     const float* __restrict__ b2, float* __restrict__ fsg) {
    if (threadIdx.x || blockIdx.x) return;
    const double inv_n = 1.0 / (double)NNODES;
    for (int j = 0; j < 7; ++j) {
        float m = (float)(ds[5 + j] * inv_n);
        float v = (float)(ds[12 + j] * inv_n) - m * m;
        float ig = (1.f / sqrtf(v + BN_EPS)) * g2[j];
        fsg[21 + j] = b2[j] - m * ig;  // c0
        fsg[28 + j] = ig;              // c1
    }
}

// ---------- node: h2 column sums ----------
__global__ void __launch_bounds__(512) k_h2sum(const float* __restrict__ x2o, const float* __restrict__ fsg,
                                               double* __restrict__ ds, int n) {
    float c0[7], c1[7];
#pragma unroll
    for (int j = 0; j < 7; ++j) { c0[j] = fsg[21 + j]; c1[j] = fsg[28 + j]; }
    double acc[7] = {0, 0, 0, 0, 0, 0, 0};
    for (int i = blockIdx.x * blockDim.x + threadIdx.x; i < n; i += gridDim.x * blockDim.x) {
        const float4* p = reinterpret_cast<const float4*>(x2o + (size_t)i * 8);
        float4 a = p[0], b = p[1];
        float x[7] = {a.x, a.y, a.z, a.w, b.x, b.y, b.z};
#pragma unroll
        for (int j = 0; j < 7; ++j) acc[j] += (double)fmaxf(x[j] * c1[j] + c0[j], 0.f);
    }
    blk_reduce_atomic<7>(acc, ds + 19);
}

// ---------- tiny: embeddings + similarity MLP + sigmoid ----------
__global__ void k_final(const double* __restrict__ ds, const float* __restrict__ Wd, const float* __restrict__ bd,
                        const float* __restrict__ Ws0, const float* __restrict__ bs0,
                        const float* __restrict__ Ws1, const float* __restrict__ bs1,
                        const float* __restrict__ Ws2, const float* __restrict__ bs2,
                        const float* __restrict__ Ws3, const float* __restrict__ bs3,
                        const float* __restrict__ Wsim, const float* __restrict__ bsim,
                        float* __restrict__ out) {
    if (threadIdx.x || blockIdx.x) return;
    const double inv_n = 1.0 / (double)NNODES;
    float v[22];
    for (int g = 0; g < 2; ++g) {
        float hm[7];
        for (int j = 0; j < 7; ++j) hm[j] = (float)(ds[g * 26 + 19 + j] * inv_n);
        for (int r = 0; r < 11; ++r) {
            float s = bd[r];
            for (int j = 0; j < 7; ++j) s += hm[j] * Wd[j * 11 + r];
            v[g * 11 + r] = s;
        }
    }
    float h[7], h2[7];
    for (int j = 0; j < 7; ++j) {
        float s = bs0[j];
        for (int k = 0; k < 22; ++k) s += v[k] * Ws0[k * 7 + j];
        h[j] = s;
    }
    const float* Ws[3] = {Ws1, Ws2, Ws3};
    const float* bs[3] = {bs1, bs2, bs3};
    for (int l = 0; l < 3; ++l) {
        for (int j = 0; j < 7; ++j) {
            float s = bs[l][j];
            for (int k = 0; k < 7; ++k) s += h[k] * Ws[l][k * 7 + j];
            h2[j] = fmaxf(s, 0.f);
        }
        for (int j = 0; j < 7; ++j) h[j] = h2[j];
    }
    for (int r = 0; r < 12; ++r) {
        float s = bsim[r];
        for (int j = 0; j < 7; ++j) s += h[j] * Wsim[j * 12 + r];
        out[r] = 1.f / (1.f + expf(-s));
    }
}

extern "C" void kernel_launch(void* const* d_in, const int* in_sizes, int n_in,
                              void* d_out, int out_size, void* d_ws, size_t ws_size,
                              hipStream_t stream) {
    const int E = in_sizes[0];
    const int n = NNODES;
    const int* src1 = (const int*)d_in[0];
    const int* dst1 = (const int*)d_in[1];
    const int* src2 = (const int*)d_in[2];
    const int* dst2 = (const int*)d_in[3];
    const float* W_init = (const float*)d_in[5];
    const float* b_init = (const float*)d_in[6];
    const float* Wg  = (const float*)d_in[7];
    const float* bg  = (const float*)d_in[8];
    const float* Wt1 = (const float*)d_in[9];
    const float* g1  = (const float*)d_in[10];
    const float* b1  = (const float*)d_in[11];
    const float* Wt2 = (const float*)d_in[12];
    const float* g2  = (const float*)d_in[13];
    const float* b2  = (const float*)d_in[14];
    const float* Wd  = (const float*)d_in[15];
    const float* bd  = (const float*)d_in[16];
    const float* Ws0 = (const float*)d_in[17];
    const float* bs0 = (const float*)d_in[18];
    const float* Ws1 = (const float*)d_in[19];
    const float* bs1 = (const float*)d_in[20];
    const float* Ws2 = (const float*)d_in[21];
    const float* bs2 = (const float*)d_in[22];
    const float* Ws3 = (const float*)d_in[23];
    const float* bs3 = (const float*)d_in[24];
    const float* Wsim = (const float*)d_in[25];
    const float* bsim = (const float*)d_in[26];

    // scalars first (1 KiB), then 16B-aligned arrays: 21n floats + 32MB pairs ≈ 74 MB
    double* dscal = (double*)d_ws;                     // 52 doubles
    float* fscal  = (float*)(dscal + 52);              // 128 floats
    float* F      = (float*)((char*)d_ws + 1024);
    float* nrm  = F;                                   // n
    float* s1   = F + (size_t)n;                       // n
    float* s1n  = F + 2 * (size_t)n;                   // n
    float* sc4  = F + 3 * (size_t)n;                   // 4n (s1,s2,nrm,sdeg)
    float* sch  = F + 7 * (size_t)n;                   // 2n float-slots = 8B fp16 (s1,s2,nrm)
    float* f1nh = F + 9 * (size_t)n;                   // 4n float-slots = 16B fp16 rows
    float* x2o  = F + 13 * (size_t)n;                  // 8n
    int*   gcnt = (int*)(F + 21 * (size_t)n);          // NBKT
    int*   bb   = gcnt + NBKT;                         // NBKT+1
    int*   gcur = bb + NBKT + 1;                       // NBKT
    unsigned int* pairs = (unsigned int*)(gcur + NBKT);// E

    const int EB = (E + EPB - 1) / EPB;

    hipMemsetAsync(dscal, 0, 52 * sizeof(double), stream);
    k_t0<<<1, 1, 0, stream>>>(W_init, b_init, Wg, bg, Wt1, fscal);

    for (int g = 0; g < 2; ++g) {
        const int* src = g ? src2 : src1;
        const int* dst = g ? dst2 : dst1;
        float* fsg  = fscal + 28 + g * 35;
        double* dsg = dscal + g * 26;

        hipMemsetAsync(gcnt, 0, NBKT * sizeof(int), stream);
        k_bhist<<<EB, 512, 0, stream>>>(dst, gcnt, E);
        k_bscan<<<1, 1024, 0, stream>>>(gcnt, bb, gcur);
        k_bscat<<<EB, 512, 0, stream>>>(src, dst, gcur, pairs, E);

        k_deg<<<NBKT, 512, 0, stream>>>(pairs, bb, nrm, sc4, n);
        k_s1 <<<NBKT, 512, 0, stream>>>(pairs, bb, nrm, s1, s1n, sc4, n);
        k_s2 <<<NBKT, 512, 0, stream>>>(pairs, bb, nrm, s1, s1n, sc4, sch, dsg, n);
        k_t1<<<1, 1, 0, stream>>>(dsg, fscal, g1, b1, fsg);
        k_f1 <<<NBKT, 512, 0, stream>>>(pairs, bb, nrm, sch, fsg, f1nh, n);
        k_x2f<<<NBKT, 512, 0, stream>>>(pairs, bb, sc4, fsg, f1nh, Wt2, x2o, dsg, n);
        k_t2<<<1, 1, 0, stream>>>(dsg, g2, b2, fsg);
        k_h2sum<<<512, 512, 0, stream>>>(x2o, fsg, dsg, n);
    }
    k_final<<<1, 1, 0, stream>>>(dscal, Wd, bd, Ws0, bs0, Ws1, bs1, Ws2, bs2, Ws3, bs3,
                                 Wsim, bsim, (float*)d_out);
}